// Round 5
// baseline (224.643 us; speedup 1.0000x reference)
//
#include <hip/hip_runtime.h>

#define N_NODES  100000
#define N_EDGES  1600000
#define N_AGENTS 50000
#define D_EDGE   48
#define D_IN     208
#define D_HID    256
#define D_OUT    64

#define AGB      32             // agents per MLP block
#define K1_PAD   224            // D_IN padded to 7*32 for MFMA K-steps
#define F_STRIDE 248            // feat LDS row stride (bf16)
#define H_STRIDE 280            // hbuf LDS row stride (bf16)

#define SCAN_ITEMS  1024
#define SCAN_BLOCKS ((N_NODES + SCAN_ITEMS - 1) / SCAN_ITEMS)   // 98
#define BUCKET_CAP  700000
#define MASKBIT     (1u << 30)
#define CNTMASK     0x3FFFFFFFu

typedef __attribute__((ext_vector_type(8))) short short8;   // 8 bf16 = 4 VGPRs
typedef __attribute__((ext_vector_type(4))) float f32x4;

static __device__ __forceinline__ unsigned short f2bf(float f) {
    unsigned u = __float_as_uint(f);
    u += 0x7FFFu + ((u >> 16) & 1u);    // round-to-nearest-even
    return (unsigned short)(u >> 16);
}

// ---------------------------------------------------------------------------
// Pack W1/W2 into MFMA-native fragment order:
//  w1p[((tile*7+ks)*64+lane)*8+j], tile=n/16: n=tile*16+(lane&15),
//  k=ks*32+(lane>>4)*8+j  ->  a wave's B-fragment load is one contiguous 1KB.
// ---------------------------------------------------------------------------
__global__ __launch_bounds__(256)
void prep_w(const float* __restrict__ W1, const float* __restrict__ W2,
            unsigned short* __restrict__ w1p, unsigned short* __restrict__ w2p) {
    int t = blockIdx.x * 256 + threadIdx.x;
    if (t < 16 * 7 * 64) {                       // W1 fragments
        int lane = t & 63;
        int ks   = (t >> 6) % 7;
        int tile = t / (7 * 64);
        int n = tile * 16 + (lane & 15);
        int kb = ks * 32 + (lane >> 4) * 8;
        unsigned short v[8];
        #pragma unroll
        for (int j = 0; j < 8; ++j) {
            int k = kb + j;
            v[j] = (k < D_IN) ? f2bf(W1[k * D_HID + n]) : (unsigned short)0;
        }
        #pragma unroll
        for (int j = 0; j < 8; ++j) w1p[t * 8 + j] = v[j];
    } else if (t < 16 * 7 * 64 + 4 * 8 * 64) {   // W2 fragments
        int u = t - 16 * 7 * 64;
        int lane = u & 63;
        int ks   = (u >> 6) & 7;
        int tile = u / (8 * 64);
        int o = tile * 16 + (lane & 15);
        int kb = ks * 32 + (lane >> 4) * 8;
        #pragma unroll
        for (int j = 0; j < 8; ++j)
            w2p[u * 8 + j] = f2bf(W2[(kb + j) * D_OUT + o]);
    }
}

// ---------------------------------------------------------------------------
// Edge-aggregation chain. Mask lives in bit 30 of cnt[].
// ---------------------------------------------------------------------------
__global__ __launch_bounds__(256)
void mask_kernel(const int* __restrict__ node_idx, int* __restrict__ cnt) {
    int i = blockIdx.x * 256 + threadIdx.x;
    if (i < N_AGENTS) atomicOr((unsigned*)&cnt[node_idx[i]], MASKBIT);
}

__global__ __launch_bounds__(256)
void hist_kernel(const int* __restrict__ row, int* __restrict__ cnt) {
    int e = blockIdx.x * 256 + threadIdx.x;
    if (e >= N_EDGES) return;
    int r = row[e];
    if (((unsigned)cnt[r]) & MASKBIT) atomicAdd(&cnt[r], 1);
}

__global__ __launch_bounds__(256)
void scan_a(const int* __restrict__ cnt, int* __restrict__ off, int* __restrict__ bsum) {
    __shared__ int s[256];
    const int b = blockIdx.x, t = threadIdx.x;
    const int base = b * SCAN_ITEMS + t * 4;
    int v[4];
    #pragma unroll
    for (int k = 0; k < 4; ++k) {
        int idx = base + k;
        unsigned c = (idx < N_NODES) ? (unsigned)cnt[idx] : 0u;
        v[k] = (c & MASKBIT) ? (int)(c & CNTMASK) : 0;
    }
    int tsum = v[0] + v[1] + v[2] + v[3];
    s[t] = tsum;
    __syncthreads();
    for (int d = 1; d < 256; d <<= 1) {
        int x = (t >= d) ? s[t - d] : 0;
        __syncthreads();
        s[t] += x;
        __syncthreads();
    }
    int run = s[t] - tsum;
    if (t == 255) bsum[b] = s[255];
    #pragma unroll
    for (int k = 0; k < 4; ++k) {
        int idx = base + k;
        if (idx < N_NODES) off[idx] = run;
        run += v[k];
    }
}

__global__ __launch_bounds__(128)
void scan_b(int* __restrict__ bsum) {
    __shared__ int s[128];
    const int t = threadIdx.x;
    int v = (t < SCAN_BLOCKS) ? bsum[t] : 0;
    s[t] = v;
    __syncthreads();
    for (int d = 1; d < 128; d <<= 1) {
        int x = (t >= d) ? s[t - d] : 0;
        __syncthreads();
        s[t] += x;
        __syncthreads();
    }
    if (t < SCAN_BLOCKS) bsum[t] = s[t] - v;   // exclusive
}

// place: off[r] is consumed as a cursor (local prefix); global base added here.
__global__ __launch_bounds__(256)
void place_kernel(const int* __restrict__ row, const int* __restrict__ cnt,
                  const int* __restrict__ bsum, int* __restrict__ off,
                  int* __restrict__ bucket) {
    int e = blockIdx.x * 256 + threadIdx.x;
    if (e >= N_EDGES) return;
    int r = row[e];
    if (!(((unsigned)cnt[r]) & MASKBIT)) return;
    int pos = atomicAdd(&off[r], 1);           // local prefix within node
    int idx = pos + bsum[r >> 10];             // + global block base
    if (idx < BUCKET_CAP) bucket[idx] = e;
}

// gather: after place, off[n] = local_start + deg; global base = off+bsum-deg.
__global__ __launch_bounds__(256)
void gather_kernel(const float* __restrict__ edge_attr,
                   const int* __restrict__ cnt,
                   const int* __restrict__ off, const int* __restrict__ bsum,
                   const int* __restrict__ bucket,
                   float* __restrict__ agg) {
    int gid = blockIdx.x * 256 + threadIdx.x;
    if (gid >= N_NODES * D_EDGE) return;
    int n = gid / D_EDGE;
    int c = gid - n * D_EDGE;
    unsigned cv = (unsigned)cnt[n];
    if (!(cv & MASKBIT)) return;               // never read by MLP
    int deg = (int)(cv & CNTMASK);
    int base = off[n] + bsum[n >> 10] - deg;
    float acc = 0.f;
    int j = 0;
    for (; j + 4 <= deg; j += 4) {
        int e0 = bucket[base + j + 0];
        int e1 = bucket[base + j + 1];
        int e2 = bucket[base + j + 2];
        int e3 = bucket[base + j + 3];
        float a0 = edge_attr[(long long)e0 * D_EDGE + c];
        float a1 = edge_attr[(long long)e1 * D_EDGE + c];
        float a2 = edge_attr[(long long)e2 * D_EDGE + c];
        float a3 = edge_attr[(long long)e3 * D_EDGE + c];
        acc += (a0 + a1) + (a2 + a3);
    }
    for (; j < deg; ++j) {
        int e0 = bucket[base + j];
        acc += edge_attr[(long long)e0 * D_EDGE + c];
    }
    agg[(long long)n * D_EDGE + c] = acc;
}

// ---------------------------------------------------------------------------
// MFMA MLP: 32 agents / 256-thread block (4 waves, 2 M-tiles).
// Layer 1: M=32, N=256, K=224. Wave w owns units [w*64, w*64+64).
// Layer 2: M=32, N=64, K=256. Wave w owns units [w*16, w*16+16).
// B-fragment loads are contiguous per wave (w1p/w2p MFMA-native layout).
// ---------------------------------------------------------------------------
__global__ __launch_bounds__(256)
void mlp_mfma(const float* __restrict__ x,
              const float* __restrict__ x_lstm,
              const float* __restrict__ z,
              const float* __restrict__ agg,
              const int* __restrict__ node_idx,
              const unsigned short* __restrict__ w1p,
              const float* __restrict__ b1,
              const unsigned short* __restrict__ w2p,
              const float* __restrict__ b2,
              float* __restrict__ out) {
    __shared__ unsigned short feat[AGB][F_STRIDE];   // 15,872 B
    __shared__ unsigned short hbuf[AGB][H_STRIDE];   // 17,920 B
    __shared__ int nidx[AGB];

    const int tid = threadIdx.x;
    const int ag0 = blockIdx.x * AGB;

    if (tid < AGB) {
        int ag = ag0 + tid;
        nidx[tid] = (ag < N_AGENTS) ? node_idx[ag] : -1;
    }
    __syncthreads();

    // ---- gather + bf16-convert: 16 threads/agent, float4 loads ----
    #pragma unroll
    for (int h = 0; h < 2; ++h) {
        const int a  = (tid >> 4) + h * 16;
        const int kt = tid & 15;
        const int nid = nidx[a];
        const int ag  = ag0 + a;
        #pragma unroll
        for (int qi = 0; qi < 4; ++qi) {
            int q = kt + qi * 16;
            if (q < 56) {
                int k = q * 4;
                float4 v = make_float4(0.f, 0.f, 0.f, 0.f);
                if (nid >= 0) {
                    if (k < 64)       v = *reinterpret_cast<const float4*>(&x[(long long)nid * 64 + k]);
                    else if (k < 128) v = *reinterpret_cast<const float4*>(&x_lstm[(long long)ag * 64 + (k - 64)]);
                    else if (k < 160) v = *reinterpret_cast<const float4*>(&z[(long long)ag * 32 + (k - 128)]);
                    else if (k < 208) v = *reinterpret_cast<const float4*>(&agg[(long long)nid * D_EDGE + (k - 160)]);
                    // k in [208,224): zero pad
                }
                ushort4 b;
                b.x = f2bf(v.x); b.y = f2bf(v.y); b.z = f2bf(v.z); b.w = f2bf(v.w);
                *reinterpret_cast<ushort4*>(&feat[a][k]) = b;
            }
        }
    }
    __syncthreads();

    const int w    = tid >> 6;      // wave 0..3
    const int lane = tid & 63;
    const int m16  = lane & 15;
    const int g    = lane >> 4;

    // ---- layer 1 ----
    short8 a0[7], a1[7];
    #pragma unroll
    for (int ks = 0; ks < 7; ++ks) {
        a0[ks] = *reinterpret_cast<const short8*>(&feat[m16][ks * 32 + g * 8]);
        a1[ks] = *reinterpret_cast<const short8*>(&feat[16 + m16][ks * 32 + g * 8]);
    }

    const short8* w1v = reinterpret_cast<const short8*>(w1p);
    #pragma unroll
    for (int nt = 0; nt < 4; ++nt) {
        const int gt = w * 4 + nt;                 // global N-tile 0..15
        f32x4 c0 = {0.f, 0.f, 0.f, 0.f};
        f32x4 c1 = {0.f, 0.f, 0.f, 0.f};
        #pragma unroll
        for (int ks = 0; ks < 7; ++ks) {
            short8 bf = w1v[(gt * 7 + ks) * 64 + lane];
            c0 = __builtin_amdgcn_mfma_f32_16x16x32_bf16(a0[ks], bf, c0, 0, 0, 0);
            c1 = __builtin_amdgcn_mfma_f32_16x16x32_bf16(a1[ks], bf, c1, 0, 0, 0);
        }
        const int n = gt * 16 + m16;
        const float bb = b1[n];
        #pragma unroll
        for (int r = 0; r < 4; ++r) {
            hbuf[g * 4 + r][n]      = f2bf(fmaxf(c0[r] + bb, 0.f));
            hbuf[16 + g * 4 + r][n] = f2bf(fmaxf(c1[r] + bb, 0.f));
        }
    }
    __syncthreads();

    // ---- layer 2 ----
    {
        short8 h0[8], h1[8];
        #pragma unroll
        for (int ks = 0; ks < 8; ++ks) {
            h0[ks] = *reinterpret_cast<const short8*>(&hbuf[m16][ks * 32 + g * 8]);
            h1[ks] = *reinterpret_cast<const short8*>(&hbuf[16 + m16][ks * 32 + g * 8]);
        }
        const short8* w2v = reinterpret_cast<const short8*>(w2p);
        f32x4 d0 = {0.f, 0.f, 0.f, 0.f};
        f32x4 d1 = {0.f, 0.f, 0.f, 0.f};
        #pragma unroll
        for (int ks = 0; ks < 8; ++ks) {
            short8 bf = w2v[(w * 8 + ks) * 64 + lane];
            d0 = __builtin_amdgcn_mfma_f32_16x16x32_bf16(h0[ks], bf, d0, 0, 0, 0);
            d1 = __builtin_amdgcn_mfma_f32_16x16x32_bf16(h1[ks], bf, d1, 0, 0, 0);
        }
        const int o = w * 16 + m16;
        const float bo = b2[o];
        #pragma unroll
        for (int r = 0; r < 4; ++r) {
            int m0 = g * 4 + r;
            int m1 = 16 + g * 4 + r;
            if (ag0 + m0 < N_AGENTS) out[(long long)(ag0 + m0) * D_OUT + o] = d0[r] + bo;
            if (ag0 + m1 < N_AGENTS) out[(long long)(ag0 + m1) * D_OUT + o] = d1[r] + bo;
        }
    }
}

extern "C" void kernel_launch(void* const* d_in, const int* in_sizes, int n_in,
                              void* d_out, int out_size, void* d_ws, size_t ws_size,
                              hipStream_t stream) {
    const float* x        = (const float*)d_in[0];
    const float* x_lstm   = (const float*)d_in[1];
    const float* z        = (const float*)d_in[2];
    const int*   edge_idx = (const int*)d_in[3];   // [2][N_EDGES]; row = first half
    const float* edge_attr= (const float*)d_in[4];
    const int*   node_idx = (const int*)d_in[5];
    const float* W1       = (const float*)d_in[6];
    const float* b1       = (const float*)d_in[7];
    const float* W2       = (const float*)d_in[8];
    const float* b2       = (const float*)d_in[9];
    float* out = (float*)d_out;

    // ws layout (256B-aligned slots)
    char* wsp = (char*)d_ws;
    size_t o = 0;
    auto alloc = [&](size_t bytes) { char* p = wsp + o; o = (o + bytes + 255) & ~(size_t)255; return p; };
    float* agg  = (float*)alloc((size_t)N_NODES * D_EDGE * 4);     // 19.2 MB
    int* cnt    = (int*)alloc((size_t)N_NODES * 4);
    int* off    = (int*)alloc((size_t)N_NODES * 4);
    int* bsum   = (int*)alloc(512);
    int* bucket = (int*)alloc((size_t)BUCKET_CAP * 4);
    unsigned short* w1p = (unsigned short*)alloc((size_t)16 * 7 * 64 * 8 * 2);  // 114,688 B
    unsigned short* w2p = (unsigned short*)alloc((size_t)4 * 8 * 64 * 8 * 2);   //  32,768 B

    hipMemsetAsync(cnt, 0, (size_t)N_NODES * 4, stream);

    prep_w<<<(16 * 7 * 64 + 4 * 8 * 64 + 255) / 256, 256, 0, stream>>>(W1, W2, w1p, w2p);
    mask_kernel<<<(N_AGENTS + 255) / 256, 256, 0, stream>>>(node_idx, cnt);
    hist_kernel<<<(N_EDGES + 255) / 256, 256, 0, stream>>>(edge_idx, cnt);
    scan_a<<<SCAN_BLOCKS, 256, 0, stream>>>(cnt, off, bsum);
    scan_b<<<1, 128, 0, stream>>>(bsum);
    place_kernel<<<(N_EDGES + 255) / 256, 256, 0, stream>>>(edge_idx, cnt, bsum, off, bucket);
    gather_kernel<<<(N_NODES * D_EDGE + 255) / 256, 256, 0, stream>>>(
        edge_attr, cnt, off, bsum, bucket, agg);
    mlp_mfma<<<(N_AGENTS + AGB - 1) / AGB, 256, 0, stream>>>(x, x_lstm, z, agg, node_idx,
                                                             w1p, b1, w2p, b2, out);
}

// Round 6
// 168.030 us; speedup vs baseline: 1.3369x; 1.3369x over previous
//
#include <hip/hip_runtime.h>

#define N_NODES  100000
#define N_EDGES  1600000
#define N_AGENTS 50000
#define D_EDGE   48
#define D_IN     208
#define D_HID    256
#define D_OUT    64

#define K1_PAD   224            // D_IN padded to 7*32 for MFMA K-steps
#define F_STRIDE 248            // feat LDS row stride (bf16)
#define H_STRIDE 280            // hbuf LDS row stride (bf16)

#define SCAN_ITEMS  1024
#define SCAN_BLOCKS ((N_NODES + SCAN_ITEMS - 1) / SCAN_ITEMS)   // 98
#define BUCKET_CAP  700000

typedef __attribute__((ext_vector_type(8))) short short8;   // 8 bf16 = 4 VGPRs
typedef __attribute__((ext_vector_type(4))) float f32x4;

static __device__ __forceinline__ unsigned short f2bf(float f) {
    unsigned u = __float_as_uint(f);
    u += 0x7FFFu + ((u >> 16) & 1u);    // round-to-nearest-even
    return (unsigned short)(u >> 16);
}

// ---------------------------------------------------------------------------
// Pack W1/W2 into MFMA-native fragment order so a wave's B-fragment load is
// one contiguous 1KB block:
//   w1p[((gt*7+ks)*64+lane)*8+j]: n=gt*16+(lane&15), k=ks*32+(lane>>4)*8+j
//   w2p[((w*8+ks)*64+lane)*8+j]:  o=w*16+(lane&15),  same k map
// ---------------------------------------------------------------------------
__global__ __launch_bounds__(256)
void prep_w(const float* __restrict__ W1, const float* __restrict__ W2,
            unsigned short* __restrict__ w1p, unsigned short* __restrict__ w2p) {
    int t = blockIdx.x * 256 + threadIdx.x;
    if (t < 16 * 7 * 64) {                       // W1 fragments
        int lane = t & 63;
        int ks   = (t >> 6) % 7;
        int tile = t / (7 * 64);
        int n = tile * 16 + (lane & 15);
        int kb = ks * 32 + (lane >> 4) * 8;
        unsigned short v[8];
        #pragma unroll
        for (int j = 0; j < 8; ++j) {
            int k = kb + j;
            v[j] = (k < D_IN) ? f2bf(W1[k * D_HID + n]) : (unsigned short)0;
        }
        #pragma unroll
        for (int j = 0; j < 8; ++j) w1p[t * 8 + j] = v[j];
    } else if (t < 16 * 7 * 64 + 4 * 8 * 64) {   // W2 fragments
        int u = t - 16 * 7 * 64;
        int lane = u & 63;
        int ks   = (u >> 6) & 7;
        int tile = u / (8 * 64);
        int o = tile * 16 + (lane & 15);
        int kb = ks * 32 + (lane >> 4) * 8;
        #pragma unroll
        for (int j = 0; j < 8; ++j)
            w2p[u * 8 + j] = f2bf(W2[(kb + j) * D_OUT + o]);
    }
}

// ---------------------------------------------------------------------------
// Edge-aggregation chain — exact round-4 structure (measured good).
// ---------------------------------------------------------------------------
__global__ __launch_bounds__(256)
void mask_kernel(const int* __restrict__ node_idx, unsigned char* __restrict__ mask) {
    int i = blockIdx.x * 256 + threadIdx.x;
    if (i < N_AGENTS) mask[node_idx[i]] = 1;
}

__global__ __launch_bounds__(256)
void hist_kernel(const int* __restrict__ row, const unsigned char* __restrict__ mask,
                 int* __restrict__ cnt) {
    int e = blockIdx.x * 256 + threadIdx.x;
    if (e >= N_EDGES) return;
    int r = row[e];
    if (mask[r]) atomicAdd(&cnt[r], 1);
}

__global__ __launch_bounds__(256)
void scan_a(const int* __restrict__ cnt, int* __restrict__ off, int* __restrict__ bsum) {
    __shared__ int s[256];
    const int b = blockIdx.x, t = threadIdx.x;
    const int base = b * SCAN_ITEMS + t * 4;
    int v[4];
    #pragma unroll
    for (int k = 0; k < 4; ++k) {
        int idx = base + k;
        v[k] = (idx < N_NODES) ? cnt[idx] : 0;
    }
    int tsum = v[0] + v[1] + v[2] + v[3];
    s[t] = tsum;
    __syncthreads();
    for (int d = 1; d < 256; d <<= 1) {
        int x = (t >= d) ? s[t - d] : 0;
        __syncthreads();
        s[t] += x;
        __syncthreads();
    }
    int run = s[t] - tsum;
    if (t == 255) bsum[b] = s[255];
    #pragma unroll
    for (int k = 0; k < 4; ++k) {
        int idx = base + k;
        if (idx < N_NODES) off[idx] = run;
        run += v[k];
    }
}

__global__ __launch_bounds__(128)
void scan_b(int* __restrict__ bsum) {
    __shared__ int s[128];
    const int t = threadIdx.x;
    int v = (t < SCAN_BLOCKS) ? bsum[t] : 0;
    s[t] = v;
    __syncthreads();
    for (int d = 1; d < 128; d <<= 1) {
        int x = (t >= d) ? s[t - d] : 0;
        __syncthreads();
        s[t] += x;
        __syncthreads();
    }
    if (t < SCAN_BLOCKS) bsum[t] = s[t] - v;
}

__global__ __launch_bounds__(256)
void scan_c(int* __restrict__ off, const int* __restrict__ bsum) {
    int i = blockIdx.x * 256 + threadIdx.x;
    if (i < N_NODES) off[i] += bsum[i / SCAN_ITEMS];
}

__global__ __launch_bounds__(256)
void place_kernel(const int* __restrict__ row, const unsigned char* __restrict__ mask,
                  const int* __restrict__ off, int* __restrict__ cur,
                  int* __restrict__ bucket) {
    int e = blockIdx.x * 256 + threadIdx.x;
    if (e >= N_EDGES) return;
    int r = row[e];
    if (!mask[r]) return;
    int pos = atomicAdd(&cur[r], 1);
    int idx = off[r] + pos;
    if (idx < BUCKET_CAP) bucket[idx] = e;
}

__global__ __launch_bounds__(256)
void gather_kernel(const float* __restrict__ edge_attr,
                   const unsigned char* __restrict__ mask,
                   const int* __restrict__ off, const int* __restrict__ cnt,
                   const int* __restrict__ bucket,
                   float* __restrict__ agg) {
    int gid = blockIdx.x * 256 + threadIdx.x;
    if (gid >= N_NODES * D_EDGE) return;
    int n = gid / D_EDGE;
    int c = gid - n * D_EDGE;
    if (!mask[n]) return;
    int deg = cnt[n];
    int base = off[n];
    float acc = 0.f;
    int j = 0;
    for (; j + 4 <= deg; j += 4) {
        int e0 = bucket[base + j + 0];
        int e1 = bucket[base + j + 1];
        int e2 = bucket[base + j + 2];
        int e3 = bucket[base + j + 3];
        float a0 = edge_attr[(long long)e0 * D_EDGE + c];
        float a1 = edge_attr[(long long)e1 * D_EDGE + c];
        float a2 = edge_attr[(long long)e2 * D_EDGE + c];
        float a3 = edge_attr[(long long)e3 * D_EDGE + c];
        acc += (a0 + a1) + (a2 + a3);
    }
    for (; j < deg; ++j) {
        int e0 = bucket[base + j];
        acc += edge_attr[(long long)e0 * D_EDGE + c];
    }
    agg[(long long)n * D_EDGE + c] = acc;
}

// ---------------------------------------------------------------------------
// MFMA MLP — exact round-4 structure (16 agents / 4 waves), ONLY change:
// B-fragments come from packed w1p/w2p (contiguous 1KB per wave-load).
// ---------------------------------------------------------------------------
__global__ __launch_bounds__(256)
void mlp_mfma(const float* __restrict__ x,
              const float* __restrict__ x_lstm,
              const float* __restrict__ z,
              const float* __restrict__ agg,
              const int* __restrict__ node_idx,
              const unsigned short* __restrict__ w1p,
              const float* __restrict__ b1,
              const unsigned short* __restrict__ w2p,
              const float* __restrict__ b2,
              float* __restrict__ out) {
    __shared__ unsigned short feat[16][F_STRIDE];   // 7,936 B
    __shared__ unsigned short hbuf[16][H_STRIDE];   // 8,960 B
    __shared__ int nidx[16];

    const int tid = threadIdx.x;
    const int ag0 = blockIdx.x * 16;

    if (tid < 16) nidx[tid] = node_idx[ag0 + tid];
    __syncthreads();

    // ---- gather + bf16-convert features: 16 threads per agent ----
    {
        const int a  = tid >> 4;
        const int kt = tid & 15;
        const int nid = nidx[a];
        const int ag  = ag0 + a;
        #pragma unroll
        for (int k = kt; k < K1_PAD; k += 16) {
            float v;
            if (k < 64)       v = x[(long long)nid * 64 + k];
            else if (k < 128) v = x_lstm[(long long)ag * 64 + (k - 64)];
            else if (k < 160) v = z[(long long)ag * 32 + (k - 128)];
            else if (k < 208) v = agg[(long long)nid * D_EDGE + (k - 160)];
            else              v = 0.f;
            feat[a][k] = f2bf(v);
        }
    }
    __syncthreads();

    const int w    = tid >> 6;      // wave 0..3
    const int lane = tid & 63;
    const int m16  = lane & 15;
    const int g    = lane >> 4;

    // ---- layer 1: M=16, N=256 (wave owns 64 units), K=224 ----
    short8 afrag[7];
    #pragma unroll
    for (int ks = 0; ks < 7; ++ks)
        afrag[ks] = *reinterpret_cast<const short8*>(&feat[m16][ks * 32 + g * 8]);

    const short8* w1v = reinterpret_cast<const short8*>(w1p);
    #pragma unroll
    for (int nt = 0; nt < 4; ++nt) {
        const int gt = w * 4 + nt;                 // global N-tile 0..15
        f32x4 acc = {0.f, 0.f, 0.f, 0.f};
        #pragma unroll
        for (int ks = 0; ks < 7; ++ks) {
            short8 bfrag = w1v[(gt * 7 + ks) * 64 + lane];
            acc = __builtin_amdgcn_mfma_f32_16x16x32_bf16(afrag[ks], bfrag, acc, 0, 0, 0);
        }
        const int n = gt * 16 + m16;
        const float bb = b1[n];
        #pragma unroll
        for (int r = 0; r < 4; ++r) {
            float h = fmaxf(acc[r] + bb, 0.f);
            hbuf[g * 4 + r][n] = f2bf(h);          // row=agent, col=unit
        }
    }
    __syncthreads();

    // ---- layer 2: M=16, N=64 (wave owns 16 units), K=256 ----
    {
        const int o = w * 16 + m16;                // output unit
        const short8* w2v = reinterpret_cast<const short8*>(w2p);
        f32x4 acc = {0.f, 0.f, 0.f, 0.f};
        #pragma unroll
        for (int ks = 0; ks < 8; ++ks) {
            short8 a2 = *reinterpret_cast<const short8*>(&hbuf[m16][ks * 32 + g * 8]);
            short8 bf = w2v[(w * 8 + ks) * 64 + lane];
            acc = __builtin_amdgcn_mfma_f32_16x16x32_bf16(a2, bf, acc, 0, 0, 0);
        }
        const float bo = b2[o];
        #pragma unroll
        for (int r = 0; r < 4; ++r) {
            const int m = g * 4 + r;               // agent row
            out[(long long)(ag0 + m) * D_OUT + o] = acc[r] + bo;
        }
    }
}

extern "C" void kernel_launch(void* const* d_in, const int* in_sizes, int n_in,
                              void* d_out, int out_size, void* d_ws, size_t ws_size,
                              hipStream_t stream) {
    const float* x        = (const float*)d_in[0];
    const float* x_lstm   = (const float*)d_in[1];
    const float* z        = (const float*)d_in[2];
    const int*   edge_idx = (const int*)d_in[3];   // [2][N_EDGES]; row = first half
    const float* edge_attr= (const float*)d_in[4];
    const int*   node_idx = (const int*)d_in[5];
    const float* W1       = (const float*)d_in[6];
    const float* b1       = (const float*)d_in[7];
    const float* W2       = (const float*)d_in[8];
    const float* b2       = (const float*)d_in[9];
    float* out = (float*)d_out;

    // ws layout (256B-aligned slots)
    char* wsp = (char*)d_ws;
    size_t o = 0;
    auto alloc = [&](size_t bytes) { char* p = wsp + o; o = (o + bytes + 255) & ~(size_t)255; return p; };
    float* agg  = (float*)alloc((size_t)N_NODES * D_EDGE * 4);     // 19.2 MB
    int* cnt    = (int*)alloc((size_t)N_NODES * 4);
    int* cur    = (int*)alloc((size_t)N_NODES * 4);
    int* off    = (int*)alloc((size_t)N_NODES * 4);
    int* bsum   = (int*)alloc(512);
    int* bucket = (int*)alloc((size_t)BUCKET_CAP * 4);
    unsigned char* mask = (unsigned char*)alloc(N_NODES);
    unsigned short* w1p = (unsigned short*)alloc((size_t)16 * 7 * 64 * 8 * 2);  // 114,688 B
    unsigned short* w2p = (unsigned short*)alloc((size_t)4 * 8 * 64 * 8 * 2);   //  32,768 B

    hipMemsetAsync(mask, 0, N_NODES, stream);
    hipMemsetAsync(cnt, 0, (size_t)N_NODES * 4, stream);
    hipMemsetAsync(cur, 0, (size_t)N_NODES * 4, stream);

    prep_w<<<(16 * 7 * 64 + 4 * 8 * 64 + 255) / 256, 256, 0, stream>>>(W1, W2, w1p, w2p);
    mask_kernel<<<(N_AGENTS + 255) / 256, 256, 0, stream>>>(node_idx, mask);
    hist_kernel<<<(N_EDGES + 255) / 256, 256, 0, stream>>>(edge_idx, mask, cnt);
    scan_a<<<SCAN_BLOCKS, 256, 0, stream>>>(cnt, off, bsum);
    scan_b<<<1, 128, 0, stream>>>(bsum);
    scan_c<<<(N_NODES + 255) / 256, 256, 0, stream>>>(off, bsum);
    place_kernel<<<(N_EDGES + 255) / 256, 256, 0, stream>>>(edge_idx, mask, off, cur, bucket);
    gather_kernel<<<(N_NODES * D_EDGE + 255) / 256, 256, 0, stream>>>(
        edge_attr, mask, off, cnt, bucket, agg);
    mlp_mfma<<<N_AGENTS / 16, 256, 0, stream>>>(x, x_lstm, z, agg, node_idx,
                                                w1p, b1, w2p, b2, out);
}